// Round 1
// baseline (317.403 us; speedup 1.0000x reference)
//
#include <hip/hip_runtime.h>

// Problem constants (match reference)
#define BB 16
#define SS 32
#define LL 128
#define DD 768
#define AA 10
#define TT 5

#define NSLOT (3 * AA)        // 30 slots: pred(10), arg0(10), arg1(10)
#define F4PR  (DD / 4)        // 192 float4 per row
#define NTHR  768             // 4 row-groups x 192 lanes

__global__ __launch_bounds__(NTHR) void srl_kernel(
    const int*   __restrict__ sent_ids,   // [B,S,L]
    const float* __restrict__ masks,      // [B,S,L]
    const float* __restrict__ emb,        // [B,S,L,D]
    const int*   __restrict__ pred_ids,   // [B,S,A,T]
    const int*   __restrict__ arg0_ids,   // [B,S,A,T]
    const int*   __restrict__ arg1_ids,   // [B,S,A,T]
    float*       __restrict__ out)        // concat: sent | pred | a0 | a1
{
    __shared__ int      s_ids[LL];
    __shared__ float    s_mask[LL];
    __shared__ unsigned s_tmask[NSLOT * TT][4];   // per (slot,t) 128-bit match mask
    __shared__ int      s_tcnt[NSLOT * TT];
    __shared__ unsigned s_smask[NSLOT][4];        // selected-t mask per slot
    __shared__ float    s_sscale[NSLOT];          // 1/count, or 0 if invalid
    __shared__ float    s_minv;                   // 1/max(sum(mask),1)
    __shared__ float4   s_red[4][F4PR];           // sent-sum partials (12 KB)

    const int bs  = blockIdx.x;          // b*S + s
    const int tid = threadIdx.x;
    const int f4c = tid % F4PR;          // float4 column within a row
    const int rq  = tid / F4PR;          // row-group 0..3 (each = 3 full waves)

    // ---- Phase A: stage ids/masks, match tokens ----
    if (tid < LL) {
        s_ids[tid]  = sent_ids[(size_t)bs * LL + tid];
        s_mask[tid] = masks[(size_t)bs * LL + tid];
    }
    __syncthreads();

    if (tid == 0) {
        float c = 0.0f;
        for (int l = 0; l < LL; ++l) c += s_mask[l];
        s_minv = 1.0f / fmaxf(c, 1.0f);
    }

    if (tid < NSLOT * TT) {
        const int slot = tid / TT;
        const int t    = tid % TT;
        const int type = slot / AA;      // 0=pred,1=arg0,2=arg1
        const int a    = slot % AA;
        const int* ap  = (type == 0) ? pred_ids : (type == 1) ? arg0_ids : arg1_ids;
        const int token = ap[((size_t)bs * AA + a) * TT + t];
        unsigned w0 = 0, w1 = 0, w2 = 0, w3 = 0;
        int cnt = 0;
        if (token != 0) {
            #pragma unroll 4
            for (int l = 0; l < LL; ++l) {
                if (s_ids[l] == token) {
                    ++cnt;
                    if      (l < 32) w0 |= 1u << l;
                    else if (l < 64) w1 |= 1u << (l - 32);
                    else if (l < 96) w2 |= 1u << (l - 64);
                    else             w3 |= 1u << (l - 96);
                }
            }
        }
        s_tmask[tid][0] = w0; s_tmask[tid][1] = w1;
        s_tmask[tid][2] = w2; s_tmask[tid][3] = w3;
        s_tcnt[tid] = cnt;
    }
    __syncthreads();

    // pick LAST valid t per slot (reference overwrites with later t)
    if (tid < NSLOT) {
        int sel = -1;
        for (int t = TT - 1; t >= 0; --t) {
            if (s_tcnt[tid * TT + t] > 0) { sel = t; break; }
        }
        if (sel >= 0) {
            const int st = tid * TT + sel;
            s_smask[tid][0] = s_tmask[st][0];
            s_smask[tid][1] = s_tmask[st][1];
            s_smask[tid][2] = s_tmask[st][2];
            s_smask[tid][3] = s_tmask[st][3];
            s_sscale[tid]   = 1.0f / (float)s_tcnt[st];
        } else {
            s_smask[tid][0] = s_smask[tid][1] = s_smask[tid][2] = s_smask[tid][3] = 0u;
            s_sscale[tid]   = 0.0f;
        }
    }
    __syncthreads();

    // ---- Phase B: stream tile once, masked sum over L ----
    const float4* embt = (const float4*)emb + (size_t)bs * LL * F4PR;
    float4 acc = make_float4(0.f, 0.f, 0.f, 0.f);
    #pragma unroll 4
    for (int l0 = 0; l0 < LL; l0 += 4) {
        const int row = l0 + rq;
        const float m = s_mask[row];
        const float4 v = embt[(size_t)row * F4PR + f4c];
        acc.x += v.x * m; acc.y += v.y * m;
        acc.z += v.z * m; acc.w += v.w * m;
    }
    s_red[rq][f4c] = acc;
    __syncthreads();

    if (tid < F4PR) {
        const float4 p0 = s_red[0][tid], p1 = s_red[1][tid];
        const float4 p2 = s_red[2][tid], p3 = s_red[3][tid];
        const float inv = s_minv;
        float4 r;
        r.x = (p0.x + p1.x + p2.x + p3.x) * inv;
        r.y = (p0.y + p1.y + p2.y + p3.y) * inv;
        r.z = (p0.z + p1.z + p2.z + p3.z) * inv;
        r.w = (p0.w + p1.w + p2.w + p3.w) * inv;
        ((float4*)out)[(size_t)bs * F4PR + tid] = r;
    }

    // ---- Phase C: per-slot gather of matched rows ----
    // output float4 bases
    const size_t O1_4 = (size_t)BB * SS * F4PR;               // after sent_avg
    const size_t OA_4 = (size_t)BB * SS * AA * F4PR;          // one arg-type span
    float4* out4 = (float4*)out;

    for (int sb = 0; sb < 32; sb += 4) {
        const int slot = sb + rq;
        if (slot >= NSLOT) continue;
        const int type = slot / AA;
        const int a    = slot % AA;
        const float scale = s_sscale[slot];
        float4 g = make_float4(0.f, 0.f, 0.f, 0.f);
        if (scale != 0.0f) {
            #pragma unroll
            for (int wi = 0; wi < 4; ++wi) {
                unsigned m = s_smask[slot][wi];
                while (m) {
                    const int l = wi * 32 + __builtin_ctz(m);
                    m &= (m - 1);
                    const float4 v = embt[(size_t)l * F4PR + f4c];
                    g.x += v.x; g.y += v.y; g.z += v.z; g.w += v.w;
                }
            }
            g.x *= scale; g.y *= scale; g.z *= scale; g.w *= scale;
        }
        const size_t base4 = O1_4 + (size_t)type * OA_4 + ((size_t)bs * AA + a) * F4PR;
        out4[base4 + f4c] = g;
    }
}

extern "C" void kernel_launch(void* const* d_in, const int* in_sizes, int n_in,
                              void* d_out, int out_size, void* d_ws, size_t ws_size,
                              hipStream_t stream) {
    const int*   sids  = (const int*)d_in[0];
    const float* masks = (const float*)d_in[1];
    const float* emb   = (const float*)d_in[2];
    const int*   pred  = (const int*)d_in[3];
    const int*   a0    = (const int*)d_in[4];
    const int*   a1    = (const int*)d_in[5];
    float* out = (float*)d_out;

    dim3 grid(BB * SS);
    dim3 block(NTHR);
    srl_kernel<<<grid, block, 0, stream>>>(sids, masks, emb, pred, a0, a1, out);
}

// Round 2
// 310.354 us; speedup vs baseline: 1.0227x; 1.0227x over previous
//
#include <hip/hip_runtime.h>

// Problem constants (match reference)
#define BB 16
#define SS 32
#define LL 128
#define DD 768
#define AA 10
#define TT 5

#define NSLOT  (3 * AA)       // 30 slots: pred(10), arg0(10), arg1(10)
#define NSPLIT 3              // split D across 3 blocks
#define F4PR   (DD / 4)       // 192 float4 per full row
#define CPH    (F4PR / NSPLIT)// 64 float4 columns per block (wave-aligned!)
#define NTHR   (4 * CPH)      // 256 threads = 4 row-groups x 64 lanes

__global__ __launch_bounds__(NTHR) void srl_kernel(
    const int*   __restrict__ sent_ids,   // [B,S,L]
    const float* __restrict__ masks,      // [B,S,L]
    const float* __restrict__ emb,        // [B,S,L,D]
    const int*   __restrict__ pred_ids,   // [B,S,A,T]
    const int*   __restrict__ arg0_ids,   // [B,S,A,T]
    const int*   __restrict__ arg1_ids,   // [B,S,A,T]
    float*       __restrict__ out)        // concat: sent | pred | a0 | a1
{
    __shared__ int      s_ids[LL];
    __shared__ float    s_mask[LL];
    __shared__ unsigned s_tmask[NSLOT * TT][4];   // per (slot,t) 128-bit match mask
    __shared__ int      s_tcnt[NSLOT * TT];
    __shared__ unsigned s_smask[NSLOT][4];        // selected-t mask per slot
    __shared__ float    s_sscale[NSLOT];          // 1/count, or 0 if invalid
    __shared__ float    s_minv;                   // 1/max(sum(mask),1)
    __shared__ float4   s_red[4][CPH];            // sent-sum partials (4 KB)

    const int bs  = blockIdx.x;          // b*S + s
    const int h   = blockIdx.y;          // D-split index 0..2
    const int tid = threadIdx.x;
    const int f4c = tid & (CPH - 1);     // float4 column within this block's span
    const int rq  = tid >> 6;            // row-group 0..3, wave-aligned (CPH==64)

    // ---- stage ids + masks ----
    if (tid < LL) {
        s_ids[tid]  = sent_ids[bs * LL + tid];
        s_mask[tid] = masks[bs * LL + tid];
    }
    __syncthreads();

    // ---- token matching (tid<150) — overlaps with the stream below ----
    if (tid < NSLOT * TT) {
        const int slot = tid / TT;
        const int t    = tid % TT;
        const int type = slot / AA;      // 0=pred,1=arg0,2=arg1
        const int a    = slot % AA;
        const int* ap  = (type == 0) ? pred_ids : (type == 1) ? arg0_ids : arg1_ids;
        const int token = ap[(bs * AA + a) * TT + t];
        unsigned w0 = 0, w1 = 0, w2 = 0, w3 = 0;
        int cnt = 0;
        if (token != 0) {
            #pragma unroll 4
            for (int l = 0; l < LL; ++l) {
                if (s_ids[l] == token) {
                    ++cnt;
                    if      (l < 32) w0 |= 1u << l;
                    else if (l < 64) w1 |= 1u << (l - 32);
                    else if (l < 96) w2 |= 1u << (l - 64);
                    else             w3 |= 1u << (l - 96);
                }
            }
        }
        s_tmask[tid][0] = w0; s_tmask[tid][1] = w1;
        s_tmask[tid][2] = w2; s_tmask[tid][3] = w3;
        s_tcnt[tid] = cnt;
    }

    // ---- stream this block's D-span once, masked sum over L ----
    const float4* embt = (const float4*)emb + (size_t)bs * LL * F4PR + h * CPH;
    float4 acc = make_float4(0.f, 0.f, 0.f, 0.f);
    #pragma unroll 8
    for (int l0 = 0; l0 < LL; l0 += 4) {
        const int row = l0 + rq;
        const float m = s_mask[row];
        const float4 v = embt[(size_t)row * F4PR + f4c];
        acc.x += v.x * m; acc.y += v.y * m;
        acc.z += v.z * m; acc.w += v.w * m;
    }
    s_red[rq][f4c] = acc;

    // ---- mask-sum via shuffle on the last wave (overlaps with others' stores) ----
    if (tid >= NTHR - 64) {
        const int lane = tid & 63;
        float pm = s_mask[lane] + s_mask[lane + 64];
        #pragma unroll
        for (int d = 32; d >= 1; d >>= 1) pm += __shfl_down(pm, d);
        if (lane == 0) s_minv = 1.0f / fmaxf(pm, 1.0f);
    }
    __syncthreads();

    // ---- wave 0: final sent reduce + write; wave 1: pick LAST valid t per slot ----
    if (tid < CPH) {
        const float4 p0 = s_red[0][tid], p1 = s_red[1][tid];
        const float4 p2 = s_red[2][tid], p3 = s_red[3][tid];
        const float inv = s_minv;
        float4 r;
        r.x = (p0.x + p1.x + p2.x + p3.x) * inv;
        r.y = (p0.y + p1.y + p2.y + p3.y) * inv;
        r.z = (p0.z + p1.z + p2.z + p3.z) * inv;
        r.w = (p0.w + p1.w + p2.w + p3.w) * inv;
        ((float4*)out)[(size_t)bs * F4PR + h * CPH + tid] = r;
    } else if (tid >= 64 && tid < 64 + NSLOT) {
        const int slot = tid - 64;
        int sel = -1;
        #pragma unroll
        for (int t = TT - 1; t >= 0; --t) {
            if (sel < 0 && s_tcnt[slot * TT + t] > 0) sel = t;
        }
        if (sel >= 0) {
            const int st = slot * TT + sel;
            s_smask[slot][0] = s_tmask[st][0];
            s_smask[slot][1] = s_tmask[st][1];
            s_smask[slot][2] = s_tmask[st][2];
            s_smask[slot][3] = s_tmask[st][3];
            s_sscale[slot]   = 1.0f / (float)s_tcnt[st];
        } else {
            s_smask[slot][0] = s_smask[slot][1] = s_smask[slot][2] = s_smask[slot][3] = 0u;
            s_sscale[slot]   = 0.0f;
        }
    }
    __syncthreads();

    // ---- per-slot gather of matched rows (wave-uniform masks: slot = sb+rq) ----
    const size_t O1_4 = (size_t)BB * SS * F4PR;       // after sent_avg
    const size_t OA_4 = (size_t)BB * SS * AA * F4PR;  // one arg-type span
    float4* out4 = (float4*)out;

    #pragma unroll
    for (int sb = 0; sb < 32; sb += 4) {
        const int slot = sb + rq;
        if (slot < NSLOT) {
            const int type = slot / AA;
            const int a    = slot % AA;
            const float scale = s_sscale[slot];
            float4 g = make_float4(0.f, 0.f, 0.f, 0.f);
            if (scale != 0.0f) {
                #pragma unroll
                for (int wi = 0; wi < 4; ++wi) {
                    unsigned m = s_smask[slot][wi];
                    while (m) {
                        const int l = (wi << 5) + __builtin_ctz(m);
                        m &= (m - 1);
                        const float4 v = embt[(size_t)l * F4PR + f4c];
                        g.x += v.x; g.y += v.y; g.z += v.z; g.w += v.w;
                    }
                }
                g.x *= scale; g.y *= scale; g.z *= scale; g.w *= scale;
            }
            out4[O1_4 + (size_t)type * OA_4 + ((size_t)bs * AA + a) * F4PR + h * CPH + f4c] = g;
        }
    }
}

extern "C" void kernel_launch(void* const* d_in, const int* in_sizes, int n_in,
                              void* d_out, int out_size, void* d_ws, size_t ws_size,
                              hipStream_t stream) {
    const int*   sids  = (const int*)d_in[0];
    const float* masks = (const float*)d_in[1];
    const float* emb   = (const float*)d_in[2];
    const int*   pred  = (const int*)d_in[3];
    const int*   a0    = (const int*)d_in[4];
    const int*   a1    = (const int*)d_in[5];
    float* out = (float*)d_out;

    dim3 grid(BB * SS, NSPLIT);
    dim3 block(NTHR);
    srl_kernel<<<grid, block, 0, stream>>>(sids, masks, emb, pred, a0, a1, out);
}